// Round 6
// baseline (1147.342 us; speedup 1.0000x reference)
//
#include <hip/hip_runtime.h>
#include <hip/hip_bf16.h>
#include <math.h>

typedef __hip_bfloat16 bf16;
typedef __attribute__((ext_vector_type(8))) short short8;   // 8 bf16 in 4 VGPRs
typedef __attribute__((ext_vector_type(4))) float f32x4;

#define BB 16
#define TT 2048
#define DM 64
#define DI 128
#define DSN 16
#define NCHK 32
#define CLEN 64

union U8 { int4 i4; unsigned short u[8]; };

__device__ __forceinline__ bf16  f2b(float v){ return __float2bfloat16(v); }
__device__ __forceinline__ float b2f(bf16 v){ return __bfloat162float(v); }
__device__ __forceinline__ unsigned short f2bu(float v){
  bf16 b = __float2bfloat16(v); unsigned short u; __builtin_memcpy(&u,&b,2); return u;
}
__device__ __forceinline__ float bu2f(unsigned short u){
  unsigned int x = ((unsigned int)u) << 16; float f; __builtin_memcpy(&f,&x,4); return f;
}
__device__ __forceinline__ float siluf(float x){ return x / (1.f + __expf(-x)); }
__device__ __forceinline__ float leakyf(float x){ return x >= 0.f ? x : 0.01f*x; }
__device__ __forceinline__ float softplusf(float x){ return x > 20.f ? x : log1pf(__expf(x)); }

__global__ __launch_bounds__(256) void k_zero(float* __restrict__ p, int n){
  int i = blockIdx.x*256 + threadIdx.x;
  if (i < n) p[i] = 0.f;
}

// ---- weight pack: (COUT,CIN,NTAP) fp32 -> B-fragment order bf16 ------------------
// fid = (k*NCH32 + ch)*NTg + cot ; lane L holds W[cot*16+(L&15)][ch*32+(L>>4)*8+j][k]
__global__ __launch_bounds__(256) void k_pack(
    const float* __restrict__ w, short* __restrict__ wp,
    int COUT, int CIN, int NTg, int NCH, int NTAP)
{
  int i = blockIdx.x*256 + threadIdx.x;
  int lane = i & 63, frag = i >> 6;
  int total = NTAP*NCH*NTg;
  if (frag >= total) return;
  int cot = frag % NTg; int kc = frag / NTg;
  int ch = kc % NCH;    int k  = kc / NCH;
  int co = cot*16 + (lane & 15);
  int ci0 = ch*32 + (lane >> 4)*8;
  unsigned short v[8];
  #pragma unroll
  for (int j = 0; j < 8; j++)
    v[j] = (co < COUT) ? f2bu(w[((size_t)co*CIN + ci0 + j)*NTAP + k]) : (unsigned short)0;
  short* dst = wp + (size_t)frag*512 + lane*8;
  *(int4*)dst = *(int4*)v;
}

// ---------------- stage 1: conv_in (12->64, k=15, pad 7) + leaky ------------------
__global__ __launch_bounds__(256) void k_conv_in(
    const float* __restrict__ x, const float* __restrict__ w,
    const float* __restrict__ bias, bf16* __restrict__ ht)
{
  __shared__ float sx[12][272];
  __shared__ float sw[12][15];
  int tid = threadIdx.x;
  int t0 = blockIdx.x * 256;
  int co = blockIdx.y;
  int b  = blockIdx.z;
  for (int i = tid; i < 12*15; i += 256) sw[i/15][i%15] = w[co*180 + i];
  for (int i = tid; i < 12*270; i += 256) {
    int ci = i/270, L = i%270;
    int tt = t0 - 7 + L;
    sx[ci][L] = (tt >= 0 && tt < TT) ? x[((size_t)b*12+ci)*TT + tt] : 0.f;
  }
  __syncthreads();
  float acc = bias[co];
  #pragma unroll
  for (int ci = 0; ci < 12; ci++) {
    #pragma unroll
    for (int k = 0; k < 15; k++)
      acc += sx[ci][tid+k]*sw[ci][k];
  }
  acc = leakyf(acc);
  int t = t0 + tid;
  ht[((size_t)b*TT + t)*DM + co] = f2b(acc);
}

// ---------- stage 2a: fused rmsnorm + in_proj MFMA (64 -> 256) --------------------
__global__ __launch_bounds__(256) void k_inproj_mfma(
    const bf16* __restrict__ ht, const float* __restrict__ nw,
    const short* __restrict__ wp, bf16* __restrict__ xm, bf16* __restrict__ z)
{
  __shared__ short sxa[64*128];
  __shared__ float sred[64][4];
  const int tid = threadIdx.x;
  const int lane = tid & 63, wv = tid >> 6;
  const int lnm = lane & 15, quad = lane >> 4;
  const size_t bt0 = (size_t)blockIdx.x * 64;

  {
    int row = tid >> 2, part = tid & 3, ch0 = part*16;
    const short* src = (const short*)ht + (bt0 + row)*64 + ch0;
    U8 p0, p1; p0.i4 = *(const int4*)src; p1.i4 = *(const int4*)(src + 8);
    float f[16]; float ss = 0.f;
    #pragma unroll
    for (int j = 0; j < 8; j++) { f[j] = bu2f(p0.u[j]); f[8+j] = bu2f(p1.u[j]); }
    #pragma unroll
    for (int j = 0; j < 16; j++) ss += f[j]*f[j];
    sred[row][part] = ss;
    __syncthreads();
    float tot = sred[row][0]+sred[row][1]+sred[row][2]+sred[row][3];
    float sc = rsqrtf(tot*(1.f/64.f) + 1e-5f);
    U8 o0, o1;
    #pragma unroll
    for (int j = 0; j < 8; j++) {
      o0.u[j] = f2bu(f[j]  *sc*nw[ch0+j]);
      o1.u[j] = f2bu(f[8+j]*sc*nw[ch0+8+j]);
    }
    int s0 = part*2, s1 = part*2+1;
    *(int4*)(sxa + row*128 + ((s0 ^ (row&7))<<3)) = o0.i4;
    *(int4*)(sxa + row*128 + ((s1 ^ (row&7))<<3)) = o1.i4;
  }
  __syncthreads();

  f32x4 acc[4][4];
  #pragma unroll
  for (int m = 0; m < 4; m++)
    #pragma unroll
    for (int n = 0; n < 4; n++) acc[m][n] = (f32x4){0.f,0.f,0.f,0.f};

  #pragma unroll
  for (int kc = 0; kc < 2; kc++) {
    short8 bfr[4];
    #pragma unroll
    for (int n = 0; n < 4; n++) {
      int fid = kc*16 + wv*4 + n;
      bfr[n] = *(const short8*)(wp + (size_t)fid*512 + lane*8);
    }
    #pragma unroll
    for (int m = 0; m < 4; m++) {
      int r2 = m*16 + lnm;
      short8 a = *(const short8*)(sxa + r2*128 + (((kc*4+quad) ^ (r2&7))<<3));
      #pragma unroll
      for (int n = 0; n < 4; n++)
        acc[m][n] = __builtin_amdgcn_mfma_f32_16x16x32_bf16(a, bfr[n], acc[m][n], 0, 0, 0);
    }
  }

  #pragma unroll
  for (int m = 0; m < 4; m++)
    #pragma unroll
    for (int n = 0; n < 4; n++) {
      int co = wv*64 + n*16 + lnm;
      float v[4] = {acc[m][n].x, acc[m][n].y, acc[m][n].z, acc[m][n].w};
      #pragma unroll
      for (int r = 0; r < 4; r++) {
        size_t t = bt0 + m*16 + quad*4 + r;
        if (co < 128) xm[t*128 + co]       = f2b(v[r]);
        else          z [t*128 + (co-128)] = f2b(v[r]);
      }
    }
}

// ---------------- stage 2b: causal depthwise conv k=4 + silu ----------------------
__global__ __launch_bounds__(256) void k_dwconv(
    const bf16* __restrict__ xm, const float* __restrict__ w,
    const float* __restrict__ bias, bf16* __restrict__ xcb)
{
  int idx = blockIdx.x*256 + threadIdx.x;        // bt*128 + c
  int c = idx & (DI-1);
  int bt = idx >> 7;
  int t = bt & (TT-1);
  float acc = bias[c];
  #pragma unroll
  for (int k = 0; k < 4; k++) {
    int tt = t - 3 + k;
    if (tt >= 0) acc += b2f(xm[(size_t)(bt - 3 + k)*DI + c]) * w[c*4+k];
  }
  xcb[idx] = f2b(siluf(acc));
}

// ---------- stage 2c: x_proj MFMA (128 -> 48, 36 valid), fp32 out -----------------
__global__ __launch_bounds__(256) void k_xproj_mfma(
    const bf16* __restrict__ xcb, const short* __restrict__ wp, float* __restrict__ xd)
{
  __shared__ __align__(16) char smem[256*64];
  const int tid = threadIdx.x;
  const int lane = tid & 63, wv = tid >> 6;
  const int lnm = lane & 15, quad = lane >> 4;
  const size_t bt0 = (size_t)blockIdx.x * 256;
  const int wvt = wv*64;

  f32x4 acc[4][3];
  #pragma unroll
  for (int m = 0; m < 4; m++)
    #pragma unroll
    for (int n = 0; n < 3; n++) acc[m][n] = (f32x4){0.f,0.f,0.f,0.f};

  for (int ch = 0; ch < 4; ch++) {
    __syncthreads();
    int sl = tid & 3;
    for (int r = tid >> 2; r < 256; r += 64) {
      int4 v = *(const int4*)((const short*)xcb + (bt0 + r)*128 + ch*32 + sl*8);
      *(int4*)(&smem[r*64 + ((sl ^ (r & 3)) << 4)]) = v;
    }
    __syncthreads();
    short8 bfr[3];
    #pragma unroll
    for (int n = 0; n < 3; n++)
      bfr[n] = *(const short8*)(wp + (size_t)(ch*3+n)*512 + lane*8);
    #pragma unroll
    for (int m = 0; m < 4; m++) {
      int row = wvt + m*16 + lnm;
      short8 a = *(const short8*)(&smem[row*64 + ((quad ^ (row & 3)) << 4)]);
      #pragma unroll
      for (int n = 0; n < 3; n++)
        acc[m][n] = __builtin_amdgcn_mfma_f32_16x16x32_bf16(a, bfr[n], acc[m][n], 0, 0, 0);
    }
  }
  #pragma unroll
  for (int m = 0; m < 4; m++)
    #pragma unroll
    for (int n = 0; n < 3; n++) {
      int cho = n*16 + lnm;
      float v[4] = {acc[m][n].x, acc[m][n].y, acc[m][n].z, acc[m][n].w};
      #pragma unroll
      for (int r = 0; r < 4; r++) {
        size_t t = bt0 + wvt + m*16 + quad*4 + r;
        xd[t*48 + cho] = v[r];
      }
    }
}

// ---------------- stage 2d: dt_proj + softplus ------------------------------------
__global__ __launch_bounds__(256) void k_delta(
    const float* __restrict__ xd, const float* __restrict__ w,
    const float* __restrict__ bias, float* __restrict__ dlt)
{
  int idx = blockIdx.x*256 + threadIdx.x;        // bt*128 + c
  int c = idx & (DI-1);
  int bt = idx >> 7;
  const float* dt = xd + (size_t)bt*48;
  float acc = bias[c];
  #pragma unroll
  for (int r = 0; r < 4; r++) acc += dt[r]*w[c*4+r];
  dlt[idx] = softplusf(acc);
}

// ---------------- stage 2e: chunked selective scan --------------------------------
__global__ __launch_bounds__(256) void k_scan_sum(
    const float* __restrict__ dlt, const bf16* __restrict__ xcb,
    const float* __restrict__ xd, const float* __restrict__ A_log,
    float* __restrict__ gP, float* __restrict__ gS)
{
  int tid = threadIdx.x;
  int n = tid & 15, dl = tid >> 4;
  int d = blockIdx.x*16 + dl;
  int b = blockIdx.y, ck = blockIdx.z;
  float A = -__expf(A_log[d*DSN + n]);
  float P = 1.f, h = 0.f;
  size_t base = (size_t)b*TT + (size_t)ck*CLEN;
  for (int i = 0; i < CLEN; i++) {
    size_t ib = base + i;
    float dd = dlt[ib*DI + d];
    float uu = b2f(xcb[ib*DI + d]);
    float Bv = xd [ib*48 + 4 + n];
    float dA = __expf(dd*A);
    h = h*dA + dd*uu*Bv;
    P *= dA;
  }
  size_t idx = (((size_t)b*NCHK + ck)*DI + d)*DSN + n;
  gP[idx] = P; gS[idx] = h;
}

__global__ __launch_bounds__(256) void k_scan_comb(
    const float* __restrict__ gP, const float* __restrict__ gS,
    float* __restrict__ ghs)
{
  int idx = blockIdx.x*256 + threadIdx.x;   // (b*128+d)*16+n
  int n = idx & 15, d = (idx >> 4) & 127, b = idx >> 11;
  float h = 0.f;
  for (int c = 0; c < NCHK; c++) {
    size_t j = (((size_t)b*NCHK + c)*DI + d)*DSN + n;
    ghs[j] = h;
    h = gP[j]*h + gS[j];
  }
}

__global__ __launch_bounds__(256) void k_scan_out(
    const float* __restrict__ dlt, const bf16* __restrict__ xcb,
    const float* __restrict__ xd, const float* __restrict__ A_log,
    const float* __restrict__ Dv, const float* __restrict__ ghs,
    bf16* __restrict__ y)
{
  int tid = threadIdx.x;
  int n = tid & 15, dl = tid >> 4;
  int d = blockIdx.x*16 + dl;
  int b = blockIdx.y, ck = blockIdx.z;
  float A = -__expf(A_log[d*DSN + n]);
  float Dd = Dv[d];
  size_t idx = (((size_t)b*NCHK + ck)*DI + d)*DSN + n;
  float h = ghs[idx];
  size_t base = (size_t)b*TT + (size_t)ck*CLEN;
  for (int i = 0; i < CLEN; i++) {
    size_t ib = base + i;
    float dd = dlt[ib*DI + d];
    float uu = b2f(xcb[ib*DI + d]);
    float Bv = xd [ib*48 + 4  + n];
    float Cv = xd [ib*48 + 20 + n];
    float dA = __expf(dd*A);
    h = h*dA + dd*uu*Bv;
    float c = h*Cv;
    c += __shfl_xor(c, 1); c += __shfl_xor(c, 2);
    c += __shfl_xor(c, 4); c += __shfl_xor(c, 8);
    if (n == 0) y[ib*DI + d] = f2b(c + uu*Dd);
  }
}

// ---------- stage 2f: gate + out_proj MFMA (128 -> 64) + residual -----------------
__global__ __launch_bounds__(256) void k_outproj_mfma(
    const bf16* __restrict__ gy, const bf16* __restrict__ gz,
    const bf16* __restrict__ ht, const short* __restrict__ wp,
    bf16* __restrict__ st)
{
  __shared__ __align__(16) char smem[256*64];
  const int tid = threadIdx.x;
  const int lane = tid & 63, wv = tid >> 6;
  const int lnm = lane & 15, quad = lane >> 4;
  const size_t bt0 = (size_t)blockIdx.x * 256;
  const int wvt = wv*64;

  f32x4 acc[4][4];
  #pragma unroll
  for (int m = 0; m < 4; m++)
    #pragma unroll
    for (int n = 0; n < 4; n++) acc[m][n] = (f32x4){0.f,0.f,0.f,0.f};

  for (int ch = 0; ch < 4; ch++) {
    __syncthreads();
    int sl = tid & 3;
    for (int r = tid >> 2; r < 256; r += 64) {
      size_t base = (bt0 + r)*(size_t)DI + ch*32 + sl*8;
      U8 yy; yy.i4 = *(const int4*)((const short*)gy + base);
      U8 zz; zz.i4 = *(const int4*)((const short*)gz + base);
      U8 o;
      #pragma unroll
      for (int j = 0; j < 8; j++)
        o.u[j] = f2bu(bu2f(yy.u[j]) * siluf(bu2f(zz.u[j])));
      *(int4*)(&smem[r*64 + ((sl ^ (r & 3)) << 4)]) = o.i4;
    }
    __syncthreads();
    short8 bfr[4];
    #pragma unroll
    for (int n = 0; n < 4; n++)
      bfr[n] = *(const short8*)(wp + (size_t)(ch*4+n)*512 + lane*8);
    #pragma unroll
    for (int m = 0; m < 4; m++) {
      int row = wvt + m*16 + lnm;
      short8 a = *(const short8*)(&smem[row*64 + ((quad ^ (row & 3)) << 4)]);
      #pragma unroll
      for (int n = 0; n < 4; n++)
        acc[m][n] = __builtin_amdgcn_mfma_f32_16x16x32_bf16(a, bfr[n], acc[m][n], 0, 0, 0);
    }
  }
  #pragma unroll
  for (int m = 0; m < 4; m++)
    #pragma unroll
    for (int n = 0; n < 4; n++) {
      int cho = n*16 + lnm;
      float v[4] = {acc[m][n].x, acc[m][n].y, acc[m][n].z, acc[m][n].w};
      #pragma unroll
      for (int r = 0; r < 4; r++) {
        size_t t = bt0 + wvt + m*16 + quad*4 + r;
        st[t*DM + cho] = f2b(v[r] + b2f(ht[t*DM + cho]));
      }
    }
}

// ================= MFMA conv15, BK=64 staging: input (B,Tlen,CIN) bf16 ============
// per barrier: 64 ci staged (270 rows x 128 B, 8-slot xor swizzle)
template<int CIN, int NSUB, int R, bool LEAKY, bool STATS, int OUTMODE>
__global__ __launch_bounds__(256) void mfma_conv(
    const bf16* __restrict__ inp, const short* __restrict__ wp,
    const float* __restrict__ bias, void* __restrict__ outv,
    float* __restrict__ stats, int Tlen, int NTg)
{
  constexpr int NCH64 = CIN/64;
  constexpr int NCH32 = CIN/32;
  constexpr int NC   = 16*NSUB;
  constexpr int NCR  = NC/R;
  constexpr int NHALF = (NC > 80) ? 2 : 1;
  constexpr int NCh  = NC/NHALF;
  constexpr int NCRh = NCR/NHALF;
  constexpr int NSUBh = NSUB/NHALF;
  constexpr int STAGE_B = 270*128;
  constexpr int EPI_B = (OUTMODE==0) ? 4*64*NCh*2 : 4*16*68*4;
  constexpr int LDSB = (STAGE_B > EPI_B) ? STAGE_B : EPI_B;
  __shared__ __align__(16) char smem[LDSB];

  const int tid  = threadIdx.x;
  const int lane = tid & 63;
  const int wv   = tid >> 6;
  const int lnm  = lane & 15;
  const int quad = lane >> 4;
  const int t0   = blockIdx.x * 256;
  const int by   = blockIdx.y;
  const int b    = blockIdx.z;
  const int wvt  = wv*64;

  f32x4 acc[4][NSUB];
  #pragma unroll
  for (int m = 0; m < 4; m++)
    #pragma unroll
    for (int n = 0; n < NSUB; n++)
      acc[m][n] = (f32x4){0.f,0.f,0.f,0.f};

  for (int ch = 0; ch < NCH64; ch++) {
    __syncthreads();
    for (int i = tid; i < 270*8; i += 256) {
      int r = i >> 3, sl = i & 7;
      int t = t0 - 7 + r;
      int4 v = {0,0,0,0};
      if (t >= 0 && t < Tlen)
        v = *(const int4*)(inp + ((size_t)b*Tlen + t)*CIN + ch*64 + sl*8);
      *(int4*)(&smem[r*128 + ((sl ^ (r & 7)) << 4)]) = v;
    }
    __syncthreads();

    for (int k = 0; k < 15; k++) {
      #pragma unroll
      for (int c2 = 0; c2 < 2; c2++) {
        short8 bfr[NSUB];
        #pragma unroll
        for (int n = 0; n < NSUB; n++) {
          size_t fid = (size_t)((k*NCH32 + ch*2 + c2)*NTg + by*NSUB + n);
          bfr[n] = *(const short8*)(wp + fid*512 + lane*8);
        }
        short8 af[4];
        #pragma unroll
        for (int m = 0; m < 4; m++) {
          int row = wvt + m*16 + lnm + k;
          af[m] = *(const short8*)(&smem[row*128 + (((c2*4+quad) ^ (row & 7)) << 4)]);
        }
        #pragma unroll
        for (int m = 0; m < 4; m++)
          #pragma unroll
          for (int n = 0; n < NSUB; n++)
            acc[m][n] = __builtin_amdgcn_mfma_f32_16x16x32_bf16(af[m], bfr[n], acc[m][n], 0, 0, 0);
      }
    }
  }

  #pragma unroll
  for (int n = 0; n < NSUB; n++) {
    float bv = bias[by*NC + n*16 + lnm];
    #pragma unroll
    for (int m = 0; m < 4; m++) {
      acc[m][n].x += bv; acc[m][n].y += bv; acc[m][n].z += bv; acc[m][n].w += bv;
    }
  }
  if (STATS) {
    #pragma unroll
    for (int n = 0; n < NSUB; n++) {
      float s1 = 0.f, s2 = 0.f;
      #pragma unroll
      for (int m = 0; m < 4; m++) {
        f32x4 a = acc[m][n];
        s1 += a.x + a.y + a.z + a.w;
        s2 += a.x*a.x + a.y*a.y + a.z*a.z + a.w*a.w;
      }
      s1 += __shfl_xor(s1, 16); s1 += __shfl_xor(s1, 32);
      s2 += __shfl_xor(s2, 16); s2 += __shfl_xor(s2, 32);
      if (quad == 0) {
        atomicAdd(&stats[by*NC + n*16 + lnm], s1);
        atomicAdd(&stats[64 + by*NC + n*16 + lnm], s2);
      }
    }
  }
  if (LEAKY) {
    #pragma unroll
    for (int m = 0; m < 4; m++)
      #pragma unroll
      for (int n = 0; n < NSUB; n++) {
        acc[m][n].x = leakyf(acc[m][n].x); acc[m][n].y = leakyf(acc[m][n].y);
        acc[m][n].z = leakyf(acc[m][n].z); acc[m][n].w = leakyf(acc[m][n].w);
      }
  }

  __syncthreads();   // staging reads complete before smem reuse

  if (OUTMODE == 0) {
    const int CTOT = NTg*16/R;
    bf16* outp = (bf16*)outv;
    size_t brow = (size_t)b * ((size_t)Tlen*R);
    #pragma unroll
    for (int h = 0; h < NHALF; h++) {
      // wave-private region: no barrier needed between halves (in-order DS per wave)
      short* Cw = (short*)smem + wv*64*NCh;
      #pragma unroll
      for (int m = 0; m < 4; m++)
        #pragma unroll
        for (int nn = 0; nn < NSUBh; nn++) {
          int n = h*NSUBh + nn;
          int cof = n*16 + lnm;          // block-local co
          int p = cof % R, c = cof / R;
          float vv[4] = {acc[m][n].x, acc[m][n].y, acc[m][n].z, acc[m][n].w};
          #pragma unroll
          for (int r = 0; r < 4; r++) {
            int t = m*16 + quad*4 + r;
            Cw[t*NCh + p*NCRh + (c - h*NCRh)] = (short)f2bu(vv[r]);
          }
        }
      const int SPT = NCh/8;
      for (int j = lane; j < 64*SPT; j += 64) {
        int t = j / SPT, sl = j % SPT;
        int cosw = sl*8;
        int p = cosw / NCRh, coff = cosw % NCRh;
        int tout = (t0 + wvt + t)*R + p;
        size_t ga = (brow + tout)*(size_t)CTOT + (size_t)by*NCR + h*NCRh + coff;
        *(int4*)((short*)outp + ga) = *(const int4*)(Cw + t*NCh + cosw);
      }
    }
  } else {
    float* Cw = (float*)smem + wv*(16*68);
    #pragma unroll
    for (int m = 0; m < 4; m++) {
      float vv[4] = {acc[m][0].x, acc[m][0].y, acc[m][0].z, acc[m][0].w};
      #pragma unroll
      for (int r = 0; r < 4; r++) {
        int t = m*16 + quad*4 + r;
        Cw[lnm*68 + t] = vv[r];
      }
    }
    float* outf = (float*)outv;
    for (int j = lane; j < 12*16; j += 64) {
      int co = j >> 4, t4 = (j & 15)*4;
      size_t ga = ((size_t)b*12 + co)*(size_t)Tlen + t0 + wvt + t4;
      *(float4*)(outf + ga) = *(const float4*)(Cw + co*68 + t4);
    }
  }
}

// ---------------- BN apply + residual; (B,T,64) bf16 out for up1 -----------------
__global__ __launch_bounds__(256) void k_bnadd2(
    const bf16* __restrict__ m2, const float* __restrict__ stats,
    const float* __restrict__ g, const float* __restrict__ bb,
    const bf16* __restrict__ ht, bf16* __restrict__ mt)
{
  int idx = blockIdx.x*256 + threadIdx.x;   // (b*T + t)*64 + c
  int c = idx & 63;
  const float cnt = (float)(BB*TT);
  float mu  = stats[c] / cnt;
  float var = stats[64+c] / cnt - mu*mu;
  float inv = rsqrtf(var + 1e-5f);
  float v = b2f(m2[idx]);
  mt[idx] = f2b((v - mu)*inv*g[c] + bb[c] + b2f(ht[idx]));
}

// ==================================================================================
extern "C" void kernel_launch(void* const* d_in, const int* in_sizes, int n_in,
                              void* d_out, int out_size, void* d_ws, size_t ws_size,
                              hipStream_t stream)
{
  const float* in_x       = (const float*)d_in[0];
  const float* conv_in_w  = (const float*)d_in[1];
  const float* conv_in_b  = (const float*)d_in[2];
  const float* norm_w     = (const float*)d_in[3];
  const float* in_proj_w  = (const float*)d_in[4];
  const float* dwconv_w   = (const float*)d_in[5];
  const float* dwconv_b   = (const float*)d_in[6];
  const float* x_proj_w   = (const float*)d_in[7];
  const float* dt_proj_w  = (const float*)d_in[8];
  const float* dt_proj_b  = (const float*)d_in[9];
  const float* A_log      = (const float*)d_in[10];
  const float* Dvec       = (const float*)d_in[11];
  const float* out_proj_w = (const float*)d_in[12];
  const float* merge_w    = (const float*)d_in[13];
  const float* merge_b    = (const float*)d_in[14];
  const float* bn_g       = (const float*)d_in[15];
  const float* bn_b       = (const float*)d_in[16];
  const float* up1_w      = (const float*)d_in[17];
  const float* up1_b      = (const float*)d_in[18];
  const float* up2_w      = (const float*)d_in[19];
  const float* up2_b      = (const float*)d_in[20];
  const float* out_w      = (const float*)d_in[21];
  const float* out_b      = (const float*)d_in[22];
  float* out = (float*)d_out;

  size_t off = 0;
  auto take = [&](size_t bytes) -> void* {
    void* p = (char*)d_ws + off;
    off += (bytes + 255) & ~(size_t)255;
    return p;
  };
  const size_t F_BDMT = (size_t)BB*DM*TT;    // 2,097,152
  const size_t F_BTDI = (size_t)BB*TT*DI;    // 4,194,304
  bf16*  g_ht  = (bf16*) take(F_BDMT*2);         // conv_in out (B,T,64), residual
  bf16*  g_st  = (bf16*) take(F_BDMT*2);         // mamba out (B,T,64)
  bf16*  g_m2  = (bf16*) take(F_BDMT*2);         // merge conv out
  bf16*  g_mt  = (bf16*) take(F_BDMT*2);         // BN+res out
  float* g_stt = (float*)take(512);
  short* wp_mg = (short*)take((size_t)15*2*4 *512*2);
  short* wp_u1 = (short*)take((size_t)15*2*100*512*2);
  short* wp_u2 = (short*)take((size_t)15*10*16*512*2);
  short* wp_oc = (short*)take((size_t)15*4*1  *512*2);
  short* wp_ip = (short*)take((size_t)1*2*16*512*2);
  short* wp_xp = (short*)take((size_t)1*4*3 *512*2);
  short* wp_op = (short*)take((size_t)1*4*4 *512*2);
  size_t mamba_base = off;
  bf16*  g_xm  = (bf16*) take(F_BTDI*2);
  bf16*  g_z   = (bf16*) take(F_BTDI*2);
  bf16*  g_xcb = (bf16*) take(F_BTDI*2);
  float* g_xd  = (float*)take((size_t)BB*TT*48*4);
  float* g_dl  = (float*)take(F_BTDI*4);
  bf16*  g_y   = (bf16*) take(F_BTDI*2);
  float* g_P   = (float*)take((size_t)BB*NCHK*DI*DSN*4);
  float* g_S   = (float*)take((size_t)BB*NCHK*DI*DSN*4);
  float* g_hs  = (float*)take((size_t)BB*NCHK*DI*DSN*4);
  // u10 overlays mamba temps (dead by up2); pad region to u10 size
  const size_t U10_B = (size_t)BB*20480*128*2;   // 83,886,080
  if (off < mamba_base + U10_B) off = mamba_base + U10_B;
  bf16*  g_u10 = (bf16*)((char*)d_ws + mamba_base);
  bf16*  g_u5  = (bf16*)take((size_t)BB*10240*320*2); // 105 MB
  if (off > ws_size) return;

  // ---- packs + stats zero ----
  k_zero<<<1, 256, 0, stream>>>(g_stt, 128);
  k_pack<<<(15*2*4*64+255)/256, 256, 0, stream>>>(merge_w, wp_mg, 64, 64, 4, 2, 15);
  k_pack<<<(15*2*100*64+255)/256, 256, 0, stream>>>(up1_w, wp_u1, 1600, 64, 100, 2, 15);
  k_pack<<<(15*10*16*64+255)/256, 256, 0, stream>>>(up2_w, wp_u2, 256, 320, 16, 10, 15);
  k_pack<<<(15*4*1*64+255)/256, 256, 0, stream>>>(out_w, wp_oc, 12, 128, 1, 4, 15);
  k_pack<<<(1*2*16*64+255)/256, 256, 0, stream>>>(in_proj_w, wp_ip, 256, 64, 16, 2, 1);
  k_pack<<<(1*4*3*64+255)/256, 256, 0, stream>>>(x_proj_w, wp_xp, 36, 128, 3, 4, 1);
  k_pack<<<(1*4*4*64+255)/256, 256, 0, stream>>>(out_proj_w, wp_op, 64, 128, 4, 4, 1);

  // ---- stage 1 ----
  k_conv_in<<<dim3(TT/256, DM, BB), 256, 0, stream>>>(in_x, conv_in_w, conv_in_b, g_ht);

  // ---- stage 2: mamba ----
  k_inproj_mfma<<<BB*TT/64, 256, 0, stream>>>(g_ht, norm_w, wp_ip, g_xm, g_z);
  k_dwconv<<<BB*TT*DI/256, 256, 0, stream>>>(g_xm, dwconv_w, dwconv_b, g_xcb);
  k_xproj_mfma<<<BB*TT/256, 256, 0, stream>>>(g_xcb, wp_xp, g_xd);
  k_delta<<<BB*TT*DI/256, 256, 0, stream>>>(g_xd, dt_proj_w, dt_proj_b, g_dl);
  k_scan_sum<<<dim3(DI/16, BB, NCHK), 256, 0, stream>>>(g_dl, g_xcb, g_xd, A_log, g_P, g_S);
  k_scan_comb<<<BB*DI*DSN/256, 256, 0, stream>>>(g_P, g_S, g_hs);
  k_scan_out<<<dim3(DI/16, BB, NCHK), 256, 0, stream>>>(g_dl, g_xcb, g_xd, A_log, Dvec, g_hs, g_y);
  k_outproj_mfma<<<BB*TT/256, 256, 0, stream>>>(g_y, g_z, g_ht, wp_op, g_st);

  // ---- stage 3: merge conv + BN + residual ----
  mfma_conv<64,4,1,false,true,0><<<dim3(TT/256, 1, BB), 256, 0, stream>>>(
      g_st, wp_mg, merge_b, g_m2, g_stt, TT, 4);
  k_bnadd2<<<BB*TT*64/256, 256, 0, stream>>>(g_m2, g_stt, bn_g, bn_b, g_ht, g_mt);

  // ---- stage 4: up1 (64 -> 1600, shuffle x5) ----
  mfma_conv<64,5,5,true,false,0><<<dim3(TT/256, 20, BB), 256, 0, stream>>>(
      g_mt, wp_u1, up1_b, g_u5, nullptr, TT, 100);

  // ---- stage 5: up2 (320 -> 256, shuffle x2), NC=128/block ----
  mfma_conv<320,8,2,true,false,0><<<dim3(TT*5/256, 2, BB), 256, 0, stream>>>(
      g_u5, wp_u2, up2_b, g_u10, nullptr, TT*5, 16);

  // ---- stage 6: out conv (128 -> 12), fp32 channel-major ----
  mfma_conv<128,1,1,false,false,1><<<dim3(TT*10/256, 1, BB), 256, 0, stream>>>(
      g_u10, wp_oc, out_b, out, nullptr, TT*10, 1);
}

// Round 7
// 826.713 us; speedup vs baseline: 1.3878x; 1.3878x over previous
//
#include <hip/hip_runtime.h>
#include <hip/hip_bf16.h>
#include <math.h>

typedef __hip_bfloat16 bf16;
typedef __attribute__((ext_vector_type(8))) short short8;   // 8 bf16 in 4 VGPRs
typedef __attribute__((ext_vector_type(4))) float f32x4;

#define BB 16
#define TT 2048
#define DM 64
#define DI 128
#define DSN 16
#define NCHK 32
#define CLEN 64

union U8 { int4 i4; unsigned short u[8]; };

__device__ __forceinline__ bf16  f2b(float v){ return __float2bfloat16(v); }
__device__ __forceinline__ float b2f(bf16 v){ return __bfloat162float(v); }
__device__ __forceinline__ unsigned short f2bu(float v){
  bf16 b = __float2bfloat16(v); unsigned short u; __builtin_memcpy(&u,&b,2); return u;
}
__device__ __forceinline__ float bu2f(unsigned short u){
  unsigned int x = ((unsigned int)u) << 16; float f; __builtin_memcpy(&f,&x,4); return f;
}
__device__ __forceinline__ float siluf(float x){ return x / (1.f + __expf(-x)); }
__device__ __forceinline__ float leakyf(float x){ return x >= 0.f ? x : 0.01f*x; }
__device__ __forceinline__ float softplusf(float x){ return x > 20.f ? x : log1pf(__expf(x)); }

// ---- fused weight pack (all 7 tensors) + stats zero ------------------------------
struct PackCfg { const float* w; short* wp; int COUT, CIN, NTg, NCH, NTAP, fragOff; };
struct PackArgs { PackCfg c[7]; int totalFrags; float* stats; };

__global__ __launch_bounds__(256) void k_pack_all(PackArgs a)
{
  int i = blockIdx.x*256 + threadIdx.x;
  if (blockIdx.x == 0 && threadIdx.x < 128) a.stats[threadIdx.x] = 0.f;
  int lane = i & 63, frag = i >> 6;
  if (frag >= a.totalFrags) return;
  int ci_ = 0;
  #pragma unroll
  for (int q = 1; q < 7; q++) if (frag >= a.c[q].fragOff) ci_ = q;
  const PackCfg& C = a.c[ci_];
  int lf = frag - C.fragOff;
  int cot = lf % C.NTg; int kc = lf / C.NTg;
  int ch = kc % C.NCH;  int k  = kc / C.NCH;
  int co = cot*16 + (lane & 15);
  int ci0 = ch*32 + (lane >> 4)*8;
  unsigned short v[8];
  #pragma unroll
  for (int j = 0; j < 8; j++)
    v[j] = (co < C.COUT) ? f2bu(C.w[((size_t)co*C.CIN + ci0 + j)*C.NTAP + k]) : (unsigned short)0;
  short* dst = C.wp + (size_t)lf*512 + lane*8;
  *(int4*)dst = *(int4*)v;
}

// ---------------- stage 1: conv_in (12->64, k=15, pad 7) + leaky ------------------
__global__ __launch_bounds__(256) void k_conv_in(
    const float* __restrict__ x, const float* __restrict__ w,
    const float* __restrict__ bias, bf16* __restrict__ ht)
{
  __shared__ float sx[12][272];
  __shared__ float sw[12][15];
  int tid = threadIdx.x;
  int t0 = blockIdx.x * 256;
  int co = blockIdx.y;
  int b  = blockIdx.z;
  for (int i = tid; i < 12*15; i += 256) sw[i/15][i%15] = w[co*180 + i];
  for (int i = tid; i < 12*270; i += 256) {
    int ci = i/270, L = i%270;
    int tt = t0 - 7 + L;
    sx[ci][L] = (tt >= 0 && tt < TT) ? x[((size_t)b*12+ci)*TT + tt] : 0.f;
  }
  __syncthreads();
  float acc = bias[co];
  #pragma unroll
  for (int ci = 0; ci < 12; ci++) {
    #pragma unroll
    for (int k = 0; k < 15; k++)
      acc += sx[ci][tid+k]*sw[ci][k];
  }
  acc = leakyf(acc);
  int t = t0 + tid;
  ht[((size_t)b*TT + t)*DM + co] = f2b(acc);
}

// ---------- stage 2a: fused rmsnorm + in_proj MFMA (64 -> 256) --------------------
__global__ __launch_bounds__(256) void k_inproj_mfma(
    const bf16* __restrict__ ht, const float* __restrict__ nw,
    const short* __restrict__ wp, bf16* __restrict__ xm, bf16* __restrict__ z)
{
  __shared__ short sxa[64*128];
  __shared__ float sred[64][4];
  const int tid = threadIdx.x;
  const int lane = tid & 63, wv = tid >> 6;
  const int lnm = lane & 15, quad = lane >> 4;
  const size_t bt0 = (size_t)blockIdx.x * 64;

  {
    int row = tid >> 2, part = tid & 3, ch0 = part*16;
    const short* src = (const short*)ht + (bt0 + row)*64 + ch0;
    U8 p0, p1; p0.i4 = *(const int4*)src; p1.i4 = *(const int4*)(src + 8);
    float f[16]; float ss = 0.f;
    #pragma unroll
    for (int j = 0; j < 8; j++) { f[j] = bu2f(p0.u[j]); f[8+j] = bu2f(p1.u[j]); }
    #pragma unroll
    for (int j = 0; j < 16; j++) ss += f[j]*f[j];
    sred[row][part] = ss;
    __syncthreads();
    float tot = sred[row][0]+sred[row][1]+sred[row][2]+sred[row][3];
    float sc = rsqrtf(tot*(1.f/64.f) + 1e-5f);
    U8 o0, o1;
    #pragma unroll
    for (int j = 0; j < 8; j++) {
      o0.u[j] = f2bu(f[j]  *sc*nw[ch0+j]);
      o1.u[j] = f2bu(f[8+j]*sc*nw[ch0+8+j]);
    }
    int s0 = part*2, s1 = part*2+1;
    *(int4*)(sxa + row*128 + ((s0 ^ (row&7))<<3)) = o0.i4;
    *(int4*)(sxa + row*128 + ((s1 ^ (row&7))<<3)) = o1.i4;
  }
  __syncthreads();

  f32x4 acc[4][4];
  #pragma unroll
  for (int m = 0; m < 4; m++)
    #pragma unroll
    for (int n = 0; n < 4; n++) acc[m][n] = (f32x4){0.f,0.f,0.f,0.f};

  #pragma unroll
  for (int kc = 0; kc < 2; kc++) {
    short8 bfr[4];
    #pragma unroll
    for (int n = 0; n < 4; n++) {
      int fid = kc*16 + wv*4 + n;
      bfr[n] = *(const short8*)(wp + (size_t)fid*512 + lane*8);
    }
    #pragma unroll
    for (int m = 0; m < 4; m++) {
      int r2 = m*16 + lnm;
      short8 a = *(const short8*)(sxa + r2*128 + (((kc*4+quad) ^ (r2&7))<<3));
      #pragma unroll
      for (int n = 0; n < 4; n++)
        acc[m][n] = __builtin_amdgcn_mfma_f32_16x16x32_bf16(a, bfr[n], acc[m][n], 0, 0, 0);
    }
  }

  #pragma unroll
  for (int m = 0; m < 4; m++)
    #pragma unroll
    for (int n = 0; n < 4; n++) {
      int co = wv*64 + n*16 + lnm;
      float v[4] = {acc[m][n].x, acc[m][n].y, acc[m][n].z, acc[m][n].w};
      #pragma unroll
      for (int r = 0; r < 4; r++) {
        size_t t = bt0 + m*16 + quad*4 + r;
        if (co < 128) xm[t*128 + co]       = f2b(v[r]);
        else          z [t*128 + (co-128)] = f2b(v[r]);
      }
    }
}

// ---------------- stage 2b: causal depthwise conv k=4 + silu ----------------------
__global__ __launch_bounds__(256) void k_dwconv(
    const bf16* __restrict__ xm, const float* __restrict__ w,
    const float* __restrict__ bias, bf16* __restrict__ xcb)
{
  int idx = blockIdx.x*256 + threadIdx.x;        // bt*128 + c
  int c = idx & (DI-1);
  int bt = idx >> 7;
  int t = bt & (TT-1);
  float acc = bias[c];
  #pragma unroll
  for (int k = 0; k < 4; k++) {
    int tt = t - 3 + k;
    if (tt >= 0) acc += b2f(xm[(size_t)(bt - 3 + k)*DI + c]) * w[c*4+k];
  }
  xcb[idx] = f2b(siluf(acc));
}

// ---------- stage 2c: x_proj MFMA (128 -> 48, 36 valid), fp32 out -----------------
__global__ __launch_bounds__(256) void k_xproj_mfma(
    const bf16* __restrict__ xcb, const short* __restrict__ wp, float* __restrict__ xd)
{
  __shared__ __align__(16) char smem[256*64];
  const int tid = threadIdx.x;
  const int lane = tid & 63, wv = tid >> 6;
  const int lnm = lane & 15, quad = lane >> 4;
  const size_t bt0 = (size_t)blockIdx.x * 256;
  const int wvt = wv*64;

  f32x4 acc[4][3];
  #pragma unroll
  for (int m = 0; m < 4; m++)
    #pragma unroll
    for (int n = 0; n < 3; n++) acc[m][n] = (f32x4){0.f,0.f,0.f,0.f};

  for (int ch = 0; ch < 4; ch++) {
    __syncthreads();
    int sl = tid & 3;
    for (int r = tid >> 2; r < 256; r += 64) {
      int4 v = *(const int4*)((const short*)xcb + (bt0 + r)*128 + ch*32 + sl*8);
      *(int4*)(&smem[r*64 + ((sl ^ (r & 3)) << 4)]) = v;
    }
    __syncthreads();
    short8 bfr[3];
    #pragma unroll
    for (int n = 0; n < 3; n++)
      bfr[n] = *(const short8*)(wp + (size_t)(ch*3+n)*512 + lane*8);
    #pragma unroll
    for (int m = 0; m < 4; m++) {
      int row = wvt + m*16 + lnm;
      short8 a = *(const short8*)(&smem[row*64 + ((quad ^ (row & 3)) << 4)]);
      #pragma unroll
      for (int n = 0; n < 3; n++)
        acc[m][n] = __builtin_amdgcn_mfma_f32_16x16x32_bf16(a, bfr[n], acc[m][n], 0, 0, 0);
    }
  }
  #pragma unroll
  for (int m = 0; m < 4; m++)
    #pragma unroll
    for (int n = 0; n < 3; n++) {
      int cho = n*16 + lnm;
      float v[4] = {acc[m][n].x, acc[m][n].y, acc[m][n].z, acc[m][n].w};
      #pragma unroll
      for (int r = 0; r < 4; r++) {
        size_t t = bt0 + wvt + m*16 + quad*4 + r;
        xd[t*48 + cho] = v[r];
      }
    }
}

// ---------------- stage 2d: dt_proj + softplus ------------------------------------
__global__ __launch_bounds__(256) void k_delta(
    const float* __restrict__ xd, const float* __restrict__ w,
    const float* __restrict__ bias, float* __restrict__ dlt)
{
  int idx = blockIdx.x*256 + threadIdx.x;        // bt*128 + c
  int c = idx & (DI-1);
  int bt = idx >> 7;
  const float* dt = xd + (size_t)bt*48;
  float acc = bias[c];
  #pragma unroll
  for (int r = 0; r < 4; r++) acc += dt[r]*w[c*4+r];
  dlt[idx] = softplusf(acc);
}

// ---------------- stage 2e: chunked selective scan --------------------------------
__global__ __launch_bounds__(256) void k_scan_sum(
    const float* __restrict__ dlt, const bf16* __restrict__ xcb,
    const float* __restrict__ xd, const float* __restrict__ A_log,
    float* __restrict__ gP, float* __restrict__ gS)
{
  int tid = threadIdx.x;
  int n = tid & 15, dl = tid >> 4;
  int d = blockIdx.x*16 + dl;
  int b = blockIdx.y, ck = blockIdx.z;
  float A = -__expf(A_log[d*DSN + n]);
  float P = 1.f, h = 0.f;
  size_t base = (size_t)b*TT + (size_t)ck*CLEN;
  for (int i = 0; i < CLEN; i++) {
    size_t ib = base + i;
    float dd = dlt[ib*DI + d];
    float uu = b2f(xcb[ib*DI + d]);
    float Bv = xd [ib*48 + 4 + n];
    float dA = __expf(dd*A);
    h = h*dA + dd*uu*Bv;
    P *= dA;
  }
  size_t idx = (((size_t)b*NCHK + ck)*DI + d)*DSN + n;
  gP[idx] = P; gS[idx] = h;
}

__global__ __launch_bounds__(256) void k_scan_comb(
    const float* __restrict__ gP, const float* __restrict__ gS,
    float* __restrict__ ghs)
{
  int idx = blockIdx.x*256 + threadIdx.x;   // (b*128+d)*16+n
  int n = idx & 15, d = (idx >> 4) & 127, b = idx >> 11;
  float h = 0.f;
  for (int c = 0; c < NCHK; c++) {
    size_t j = (((size_t)b*NCHK + c)*DI + d)*DSN + n;
    ghs[j] = h;
    h = gP[j]*h + gS[j];
  }
}

__global__ __launch_bounds__(256) void k_scan_out(
    const float* __restrict__ dlt, const bf16* __restrict__ xcb,
    const float* __restrict__ xd, const float* __restrict__ A_log,
    const float* __restrict__ Dv, const float* __restrict__ ghs,
    bf16* __restrict__ y)
{
  int tid = threadIdx.x;
  int n = tid & 15, dl = tid >> 4;
  int d = blockIdx.x*16 + dl;
  int b = blockIdx.y, ck = blockIdx.z;
  float A = -__expf(A_log[d*DSN + n]);
  float Dd = Dv[d];
  size_t idx = (((size_t)b*NCHK + ck)*DI + d)*DSN + n;
  float h = ghs[idx];
  size_t base = (size_t)b*TT + (size_t)ck*CLEN;
  for (int i = 0; i < CLEN; i++) {
    size_t ib = base + i;
    float dd = dlt[ib*DI + d];
    float uu = b2f(xcb[ib*DI + d]);
    float Bv = xd [ib*48 + 4  + n];
    float Cv = xd [ib*48 + 20 + n];
    float dA = __expf(dd*A);
    h = h*dA + dd*uu*Bv;
    float c = h*Cv;
    c += __shfl_xor(c, 1); c += __shfl_xor(c, 2);
    c += __shfl_xor(c, 4); c += __shfl_xor(c, 8);
    if (n == 0) y[ib*DI + d] = f2b(c + uu*Dd);
  }
}

// ---------- stage 2f: gate + out_proj MFMA (128 -> 64) + residual -----------------
__global__ __launch_bounds__(256) void k_outproj_mfma(
    const bf16* __restrict__ gy, const bf16* __restrict__ gz,
    const bf16* __restrict__ ht, const short* __restrict__ wp,
    bf16* __restrict__ st)
{
  __shared__ __align__(16) char smem[256*64];
  const int tid = threadIdx.x;
  const int lane = tid & 63, wv = tid >> 6;
  const int lnm = lane & 15, quad = lane >> 4;
  const size_t bt0 = (size_t)blockIdx.x * 256;
  const int wvt = wv*64;

  f32x4 acc[4][4];
  #pragma unroll
  for (int m = 0; m < 4; m++)
    #pragma unroll
    for (int n = 0; n < 4; n++) acc[m][n] = (f32x4){0.f,0.f,0.f,0.f};

  for (int ch = 0; ch < 4; ch++) {
    __syncthreads();
    int sl = tid & 3;
    for (int r = tid >> 2; r < 256; r += 64) {
      size_t base = (bt0 + r)*(size_t)DI + ch*32 + sl*8;
      U8 yy; yy.i4 = *(const int4*)((const short*)gy + base);
      U8 zz; zz.i4 = *(const int4*)((const short*)gz + base);
      U8 o;
      #pragma unroll
      for (int j = 0; j < 8; j++)
        o.u[j] = f2bu(bu2f(yy.u[j]) * siluf(bu2f(zz.u[j])));
      *(int4*)(&smem[r*64 + ((sl ^ (r & 3)) << 4)]) = o.i4;
    }
    __syncthreads();
    short8 bfr[4];
    #pragma unroll
    for (int n = 0; n < 4; n++)
      bfr[n] = *(const short8*)(wp + (size_t)(ch*4+n)*512 + lane*8);
    #pragma unroll
    for (int m = 0; m < 4; m++) {
      int row = wvt + m*16 + lnm;
      short8 a = *(const short8*)(&smem[row*64 + ((quad ^ (row & 3)) << 4)]);
      #pragma unroll
      for (int n = 0; n < 4; n++)
        acc[m][n] = __builtin_amdgcn_mfma_f32_16x16x32_bf16(a, bfr[n], acc[m][n], 0, 0, 0);
    }
  }
  #pragma unroll
  for (int m = 0; m < 4; m++)
    #pragma unroll
    for (int n = 0; n < 4; n++) {
      int cho = n*16 + lnm;
      float v[4] = {acc[m][n].x, acc[m][n].y, acc[m][n].z, acc[m][n].w};
      #pragma unroll
      for (int r = 0; r < 4; r++) {
        size_t t = bt0 + wvt + m*16 + quad*4 + r;
        st[t*DM + cho] = f2b(v[r] + b2f(ht[t*DM + cho]));
      }
    }
}

// ================= MFMA conv15, BK=32, 80B-padded stage (conflict-free) ===========
// T-split epilogue (two 32-row halves, wave-private LDS, no extra barriers).
template<int CIN, int NSUB, int R, bool LEAKY, bool STATS, int OUTMODE>
__global__ __launch_bounds__(256) void mfma_conv(
    const bf16* __restrict__ inp, const short* __restrict__ wp,
    const float* __restrict__ bias, void* __restrict__ outv,
    float* __restrict__ stats, int Tlen, int NTg)
{
  constexpr int NCH = CIN/32;
  constexpr int NC  = 16*NSUB;
  constexpr int NCR = NC/R;
  constexpr int ROWW = 40;                     // shorts per stage row (80 B = 20 banks)
  constexpr int STAGE_B = 270*ROWW*2;          // 21600 B
  constexpr int EPI_B = (OUTMODE==0) ? 4*32*NC*2 : 4*16*68*4;
  constexpr int LDSB = (STAGE_B > EPI_B) ? STAGE_B : EPI_B;
  __shared__ __align__(16) char smem[LDSB];
  short* sx = (short*)smem;

  const int tid  = threadIdx.x;
  const int lane = tid & 63;
  const int wv   = tid >> 6;
  const int lnm  = lane & 15;
  const int quad = lane >> 4;
  const int t0   = blockIdx.x * 256;
  const int by   = blockIdx.y;
  const int b    = blockIdx.z;
  const int wvt  = wv*64;

  f32x4 acc[4][NSUB];
  #pragma unroll
  for (int m = 0; m < 4; m++)
    #pragma unroll
    for (int n = 0; n < NSUB; n++)
      acc[m][n] = (f32x4){0.f,0.f,0.f,0.f};

  for (int ch = 0; ch < NCH; ch++) {
    __syncthreads();
    {
      int sl = tid & 3;
      for (int r = tid >> 2; r < 270; r += 64) {
        int t = t0 - 7 + r;
        int4 v = {0,0,0,0};
        if (t >= 0 && t < Tlen)
          v = *(const int4*)(inp + ((size_t)b*Tlen + t)*CIN + ch*32 + sl*8);
        *(int4*)(sx + r*ROWW + sl*8) = v;
      }
    }
    __syncthreads();

    short8 bcur[NSUB], bnxt[NSUB];
    #pragma unroll
    for (int n = 0; n < NSUB; n++) {
      size_t fid = (size_t)((0*NCH + ch)*NTg + by*NSUB + n);
      bcur[n] = *(const short8*)(wp + fid*512 + lane*8);
    }
    for (int k = 0; k < 15; k++) {
      if (k < 14) {
        #pragma unroll
        for (int n = 0; n < NSUB; n++) {
          size_t fid = (size_t)(((k+1)*NCH + ch)*NTg + by*NSUB + n);
          bnxt[n] = *(const short8*)(wp + fid*512 + lane*8);
        }
      }
      short8 af[4];
      #pragma unroll
      for (int m = 0; m < 4; m++) {
        int row = wvt + m*16 + lnm + k;
        af[m] = *(const short8*)(sx + row*ROWW + quad*8);
      }
      #pragma unroll
      for (int m = 0; m < 4; m++)
        #pragma unroll
        for (int n = 0; n < NSUB; n++)
          acc[m][n] = __builtin_amdgcn_mfma_f32_16x16x32_bf16(af[m], bcur[n], acc[m][n], 0, 0, 0);
      #pragma unroll
      for (int n = 0; n < NSUB; n++) bcur[n] = bnxt[n];
    }
  }

  #pragma unroll
  for (int n = 0; n < NSUB; n++) {
    float bv = bias[by*NC + n*16 + lnm];
    #pragma unroll
    for (int m = 0; m < 4; m++) {
      acc[m][n].x += bv; acc[m][n].y += bv; acc[m][n].z += bv; acc[m][n].w += bv;
    }
  }
  if (STATS) {
    #pragma unroll
    for (int n = 0; n < NSUB; n++) {
      float s1 = 0.f, s2 = 0.f;
      #pragma unroll
      for (int m = 0; m < 4; m++) {
        f32x4 a = acc[m][n];
        s1 += a.x + a.y + a.z + a.w;
        s2 += a.x*a.x + a.y*a.y + a.z*a.z + a.w*a.w;
      }
      s1 += __shfl_xor(s1, 16); s1 += __shfl_xor(s1, 32);
      s2 += __shfl_xor(s2, 16); s2 += __shfl_xor(s2, 32);
      if (quad == 0) {
        atomicAdd(&stats[by*NC + n*16 + lnm], s1);
        atomicAdd(&stats[64 + by*NC + n*16 + lnm], s2);
      }
    }
  }
  if (LEAKY) {
    #pragma unroll
    for (int m = 0; m < 4; m++)
      #pragma unroll
      for (int n = 0; n < NSUB; n++) {
        acc[m][n].x = leakyf(acc[m][n].x); acc[m][n].y = leakyf(acc[m][n].y);
        acc[m][n].z = leakyf(acc[m][n].z); acc[m][n].w = leakyf(acc[m][n].w);
      }
  }

  __syncthreads();   // staging reads complete before smem reuse

  if (OUTMODE == 0) {
    const int CTOT = NTg*16/R;
    bf16* outp = (bf16*)outv;
    size_t brow = (size_t)b * ((size_t)Tlen*R);
    short* Cw = (short*)smem + wv*32*NC;   // wave-private 32-row half
    #pragma unroll
    for (int h = 0; h < 2; h++) {
      #pragma unroll
      for (int mm = 0; mm < 2; mm++) {
        int m = h*2 + mm;
        #pragma unroll
        for (int n = 0; n < NSUB; n++) {
          int cof = n*16 + lnm;
          int p = cof % R, c = cof / R;
          float vv[4] = {acc[m][n].x, acc[m][n].y, acc[m][n].z, acc[m][n].w};
          #pragma unroll
          for (int r = 0; r < 4; r++) {
            int t = mm*16 + quad*4 + r;
            Cw[t*NC + p*NCR + c] = (short)f2bu(vv[r]);
          }
        }
      }
      const int SPT = NC/8;
      for (int j = lane; j < 32*SPT; j += 64) {
        int t = j / SPT, sl = j % SPT;
        int cosw = sl*8;
        int p = cosw / NCR, coff = cosw % NCR;
        int tout = (t0 + wvt + h*32 + t)*R + p;
        size_t ga = (brow + tout)*(size_t)CTOT + (size_t)by*NCR + coff;
        *(int4*)((short*)outp + ga) = *(const int4*)(Cw + t*NC + cosw);
      }
    }
  } else {
    float* Cw = (float*)smem + wv*(16*68);
    #pragma unroll
    for (int m = 0; m < 4; m++) {
      float vv[4] = {acc[m][0].x, acc[m][0].y, acc[m][0].z, acc[m][0].w};
      #pragma unroll
      for (int r = 0; r < 4; r++) {
        int t = m*16 + quad*4 + r;
        Cw[lnm*68 + t] = vv[r];
      }
    }
    float* outf = (float*)outv;
    for (int j = lane; j < 12*16; j += 64) {
      int co = j >> 4, t4 = (j & 15)*4;
      size_t ga = ((size_t)b*12 + co)*(size_t)Tlen + t0 + wvt + t4;
      *(float4*)(outf + ga) = *(const float4*)(Cw + co*68 + t4);
    }
  }
}

// ---------------- BN apply + residual; (B,T,64) bf16 out for up1 -----------------
__global__ __launch_bounds__(256) void k_bnadd2(
    const bf16* __restrict__ m2, const float* __restrict__ stats,
    const float* __restrict__ g, const float* __restrict__ bb,
    const bf16* __restrict__ ht, bf16* __restrict__ mt)
{
  int idx = blockIdx.x*256 + threadIdx.x;   // (b*T + t)*64 + c
  int c = idx & 63;
  const float cnt = (float)(BB*TT);
  float mu  = stats[c] / cnt;
  float var = stats[64+c] / cnt - mu*mu;
  float inv = rsqrtf(var + 1e-5f);
  float v = b2f(m2[idx]);
  mt[idx] = f2b((v - mu)*inv*g[c] + bb[c] + b2f(ht[idx]));
}

// ==================================================================================
extern "C" void kernel_launch(void* const* d_in, const int* in_sizes, int n_in,
                              void* d_out, int out_size, void* d_ws, size_t ws_size,
                              hipStream_t stream)
{
  const float* in_x       = (const float*)d_in[0];
  const float* conv_in_w  = (const float*)d_in[1];
  const float* conv_in_b  = (const float*)d_in[2];
  const float* norm_w     = (const float*)d_in[3];
  const float* in_proj_w  = (const float*)d_in[4];
  const float* dwconv_w   = (const float*)d_in[5];
  const float* dwconv_b   = (const float*)d_in[6];
  const float* x_proj_w   = (const float*)d_in[7];
  const float* dt_proj_w  = (const float*)d_in[8];
  const float* dt_proj_b  = (const float*)d_in[9];
  const float* A_log      = (const float*)d_in[10];
  const float* Dvec       = (const float*)d_in[11];
  const float* out_proj_w = (const float*)d_in[12];
  const float* merge_w    = (const float*)d_in[13];
  const float* merge_b    = (const float*)d_in[14];
  const float* bn_g       = (const float*)d_in[15];
  const float* bn_b       = (const float*)d_in[16];
  const float* up1_w      = (const float*)d_in[17];
  const float* up1_b      = (const float*)d_in[18];
  const float* up2_w      = (const float*)d_in[19];
  const float* up2_b      = (const float*)d_in[20];
  const float* out_w      = (const float*)d_in[21];
  const float* out_b      = (const float*)d_in[22];
  float* out = (float*)d_out;

  size_t off = 0;
  auto take = [&](size_t bytes) -> void* {
    void* p = (char*)d_ws + off;
    off += (bytes + 255) & ~(size_t)255;
    return p;
  };
  const size_t F_BDMT = (size_t)BB*DM*TT;    // 2,097,152
  const size_t F_BTDI = (size_t)BB*TT*DI;    // 4,194,304
  bf16*  g_ht  = (bf16*) take(F_BDMT*2);         // conv_in out (B,T,64), residual
  bf16*  g_st  = (bf16*) take(F_BDMT*2);         // mamba out (B,T,64)
  bf16*  g_m2  = (bf16*) take(F_BDMT*2);         // merge conv out
  bf16*  g_mt  = (bf16*) take(F_BDMT*2);         // BN+res out
  float* g_stt = (float*)take(512);
  short* wp_mg = (short*)take((size_t)15*2*4 *512*2);
  short* wp_u1 = (short*)take((size_t)15*2*100*512*2);
  short* wp_u2 = (short*)take((size_t)15*10*16*512*2);
  short* wp_oc = (short*)take((size_t)15*4*1  *512*2);
  short* wp_ip = (short*)take((size_t)1*2*16*512*2);
  short* wp_xp = (short*)take((size_t)1*4*3 *512*2);
  short* wp_op = (short*)take((size_t)1*4*4 *512*2);
  size_t mamba_base = off;
  bf16*  g_xm  = (bf16*) take(F_BTDI*2);
  bf16*  g_z   = (bf16*) take(F_BTDI*2);
  bf16*  g_xcb = (bf16*) take(F_BTDI*2);
  float* g_xd  = (float*)take((size_t)BB*TT*48*4);
  float* g_dl  = (float*)take(F_BTDI*4);
  bf16*  g_y   = (bf16*) take(F_BTDI*2);
  float* g_P   = (float*)take((size_t)BB*NCHK*DI*DSN*4);
  float* g_S   = (float*)take((size_t)BB*NCHK*DI*DSN*4);
  float* g_hs  = (float*)take((size_t)BB*NCHK*DI*DSN*4);
  const size_t U10_B = (size_t)BB*20480*128*2;   // 83,886,080
  if (off < mamba_base + U10_B) off = mamba_base + U10_B;
  bf16*  g_u10 = (bf16*)((char*)d_ws + mamba_base);
  bf16*  g_u5  = (bf16*)take((size_t)BB*10240*320*2); // 105 MB
  if (off > ws_size) return;

  // ---- fused pack (7 tensors) + stats zero ----
  {
    PackArgs pa;
    int o0 = 0;
    auto C = [&](int i, const float* w, short* wp, int COUT, int CIN, int NTg, int NCH, int NTAP){
      pa.c[i] = {w, wp, COUT, CIN, NTg, NCH, NTAP, o0};
      o0 += NTAP*NCH*NTg;
    };
    C(0, merge_w,    wp_mg, 64,   64,  4,   2,  15);
    C(1, up1_w,      wp_u1, 1600, 64,  100, 2,  15);
    C(2, up2_w,      wp_u2, 256,  320, 16,  10, 15);
    C(3, out_w,      wp_oc, 12,   128, 1,   4,  15);
    C(4, in_proj_w,  wp_ip, 256,  64,  16,  2,  1);
    C(5, x_proj_w,   wp_xp, 36,   128, 3,   4,  1);
    C(6, out_proj_w, wp_op, 64,   128, 4,   4,  1);
    pa.totalFrags = o0;
    pa.stats = g_stt;
    k_pack_all<<<(o0*64 + 255)/256, 256, 0, stream>>>(pa);
  }

  // ---- stage 1 ----
  k_conv_in<<<dim3(TT/256, DM, BB), 256, 0, stream>>>(in_x, conv_in_w, conv_in_b, g_ht);

  // ---- stage 2: mamba ----
  k_inproj_mfma<<<BB*TT/64, 256, 0, stream>>>(g_ht, norm_w, wp_ip, g_xm, g_z);
  k_dwconv<<<BB*TT*DI/256, 256, 0, stream>>>(g_xm, dwconv_w, dwconv_b, g_xcb);
  k_xproj_mfma<<<BB*TT/256, 256, 0, stream>>>(g_xcb, wp_xp, g_xd);
  k_delta<<<BB*TT*DI/256, 256, 0, stream>>>(g_xd, dt_proj_w, dt_proj_b, g_dl);
  k_scan_sum<<<dim3(DI/16, BB, NCHK), 256, 0, stream>>>(g_dl, g_xcb, g_xd, A_log, g_P, g_S);
  k_scan_comb<<<BB*DI*DSN/256, 256, 0, stream>>>(g_P, g_S, g_hs);
  k_scan_out<<<dim3(DI/16, BB, NCHK), 256, 0, stream>>>(g_dl, g_xcb, g_xd, A_log, Dvec, g_hs, g_y);
  k_outproj_mfma<<<BB*TT/256, 256, 0, stream>>>(g_y, g_z, g_ht, wp_op, g_st);

  // ---- stage 3: merge conv + BN + residual ----
  mfma_conv<64,4,1,false,true,0><<<dim3(TT/256, 1, BB), 256, 0, stream>>>(
      g_st, wp_mg, merge_b, g_m2, g_stt, TT, 4);
  k_bnadd2<<<BB*TT*64/256, 256, 0, stream>>>(g_m2, g_stt, bn_g, bn_b, g_ht, g_mt);

  // ---- stage 4: up1 (64 -> 1600, shuffle x5) ----
  mfma_conv<64,5,5,true,false,0><<<dim3(TT/256, 20, BB), 256, 0, stream>>>(
      g_mt, wp_u1, up1_b, g_u5, nullptr, TT, 100);

  // ---- stage 5: up2 (320 -> 256, shuffle x2) ----
  mfma_conv<320,4,2,true,false,0><<<dim3(TT*5/256, 4, BB), 256, 0, stream>>>(
      g_u5, wp_u2, up2_b, g_u10, nullptr, TT*5, 16);

  // ---- stage 6: out conv (128 -> 12), fp32 channel-major ----
  mfma_conv<128,1,1,false,false,1><<<dim3(TT*10/256, 1, BB), 256, 0, stream>>>(
      g_u10, wp_oc, out_b, out, nullptr, TT*10, 1);
}